// Round 1
// baseline (1981.409 us; speedup 1.0000x reference)
//
#include <hip/hip_runtime.h>
#include <hip/hip_bf16.h>

// Problem: B=8, N=4096, IN_DIM=256, HID=256, all fp32.
// out[b,h] = sum_k w[b,k] * V[b,k,h],  w[b,k] = (1/N) sum_q softmax_row_q(QK^T*scale)[k]
// Scores are small (std~0.33 after scale, |s|<~3) -> exp without max-subtraction is safe in fp32.

#define NTOK 4096
#define HDIM 256
#define NBATCH 8
#define SCALE 0.0625f  // 1/sqrt(256)

// ---------------- zero init (w, l, out are accumulated atomically) ----------------
__global__ void zero_kernel(float* __restrict__ w, float* __restrict__ l, float* __restrict__ out) {
    int i = blockIdx.x * 256 + threadIdx.x;   // grid covers 32768
    w[i] = 0.f;
    l[i] = 0.f;
    if (i < NBATCH * HDIM) out[i] = 0.f;
}

// ---------------- QKV projection: [32768,256] @ [256,256] + bias, z selects Q/K/V ----------------
__global__ __launch_bounds__(256) void qkv_gemm(
    const float* __restrict__ x,
    const float* __restrict__ Wq, const float* __restrict__ bq,
    const float* __restrict__ Wk, const float* __restrict__ bk,
    const float* __restrict__ Wv, const float* __restrict__ bv,
    float* __restrict__ Q, float* __restrict__ K, float* __restrict__ V) {
    const int z = blockIdx.z;
    const float* W    = (z == 0) ? Wq : (z == 1) ? Wk : Wv;
    const float* bias = (z == 0) ? bq : (z == 1) ? bk : bv;
    float* out        = (z == 0) ? Q  : (z == 1) ? K  : V;

    const int m0 = blockIdx.x * 128;
    const int n0 = blockIdx.y * 128;
    const int t  = threadIdx.x;
    const int tx = t & 15, ty = t >> 4;

    __shared__ float xs[32][132];   // [d][m], pad 132 keeps 16B alignment for b128 reads
    __shared__ float wsm[32][132];  // [d][n]

    float acc[8][8];
#pragma unroll
    for (int i = 0; i < 8; ++i)
#pragma unroll
        for (int j = 0; j < 8; ++j) acc[i][j] = 0.f;

    for (int dc = 0; dc < 8; ++dc) {
        const int dbase = dc * 32;
        __syncthreads();
        // stage x tile: 128 rows x 32 d
#pragma unroll
        for (int i = 0; i < 4; ++i) {
            int f = t + i * 256;
            int m = f >> 3;
            int d4 = (f & 7) << 2;
            float4 v = *(const float4*)(x + (size_t)(m0 + m) * HDIM + dbase + d4);
            xs[d4 + 0][m] = v.x; xs[d4 + 1][m] = v.y; xs[d4 + 2][m] = v.z; xs[d4 + 3][m] = v.w;
        }
        // stage W tile: 32 d x 128 n
#pragma unroll
        for (int i = 0; i < 4; ++i) {
            int f = t + i * 256;
            int d = f >> 5;
            int n4 = (f & 31) << 2;
            float4 v = *(const float4*)(W + (size_t)(dbase + d) * HDIM + n0 + n4);
            wsm[d][n4 + 0] = v.x; wsm[d][n4 + 1] = v.y; wsm[d][n4 + 2] = v.z; wsm[d][n4 + 3] = v.w;
        }
        __syncthreads();
#pragma unroll 4
        for (int d = 0; d < 32; ++d) {
            float4 a0 = *(const float4*)&xs[d][ty * 4];
            float4 a1 = *(const float4*)&xs[d][64 + ty * 4];
            float4 b0 = *(const float4*)&wsm[d][tx * 4];
            float4 b1 = *(const float4*)&wsm[d][64 + tx * 4];
            float av[8] = {a0.x, a0.y, a0.z, a0.w, a1.x, a1.y, a1.z, a1.w};
            float bv2[8] = {b0.x, b0.y, b0.z, b0.w, b1.x, b1.y, b1.z, b1.w};
#pragma unroll
            for (int i = 0; i < 8; ++i)
#pragma unroll
                for (int j = 0; j < 8; ++j) acc[i][j] = fmaf(av[i], bv2[j], acc[i][j]);
        }
    }
    float4 bb0 = *(const float4*)(bias + n0 + tx * 4);
    float4 bb1 = *(const float4*)(bias + n0 + 64 + tx * 4);
#pragma unroll
    for (int i = 0; i < 8; ++i) {
        int row = m0 + ty * 4 + (i & 3) + (i >> 2) * 64;
        float4 s0 = make_float4(acc[i][0] + bb0.x, acc[i][1] + bb0.y, acc[i][2] + bb0.z, acc[i][3] + bb0.w);
        float4 s1 = make_float4(acc[i][4] + bb1.x, acc[i][5] + bb1.y, acc[i][6] + bb1.z, acc[i][7] + bb1.w);
        *(float4*)(out + (size_t)row * HDIM + n0 + tx * 4) = s0;
        *(float4*)(out + (size_t)row * HDIM + n0 + 64 + tx * 4) = s1;
    }
}

// ---------------- pass 1: l[b,q] = sum_k exp(scale * Q[q,:].K[k,:]) ----------------
__global__ __launch_bounds__(256) void score_pass1(const float* __restrict__ Q,
                                                   const float* __restrict__ K,
                                                   float* __restrict__ l) {
    const int b = blockIdx.z;
    const int q0 = blockIdx.x * 128;
    const int kbase = blockIdx.y * 2048;
    const int t = threadIdx.x;
    const int tx = t & 15, ty = t >> 4;
    const float* Qb = Q + (size_t)b * NTOK * HDIM;
    const float* Kb = K + (size_t)b * NTOK * HDIM;

    __shared__ float qs[32][132];
    __shared__ float ks[32][132];

    float rsum[8];
#pragma unroll
    for (int i = 0; i < 8; ++i) rsum[i] = 0.f;

    for (int kt = 0; kt < 16; ++kt) {
        const int k0 = kbase + kt * 128;
        float acc[8][8];
#pragma unroll
        for (int i = 0; i < 8; ++i)
#pragma unroll
            for (int j = 0; j < 8; ++j) acc[i][j] = 0.f;

        for (int dc = 0; dc < 8; ++dc) {
            const int dbase = dc * 32;
            __syncthreads();
#pragma unroll
            for (int i = 0; i < 4; ++i) {
                int f = t + i * 256;
                int m = f >> 3;
                int d4 = (f & 7) << 2;
                float4 v = *(const float4*)(Qb + (size_t)(q0 + m) * HDIM + dbase + d4);
                qs[d4 + 0][m] = v.x; qs[d4 + 1][m] = v.y; qs[d4 + 2][m] = v.z; qs[d4 + 3][m] = v.w;
                float4 u = *(const float4*)(Kb + (size_t)(k0 + m) * HDIM + dbase + d4);
                ks[d4 + 0][m] = u.x; ks[d4 + 1][m] = u.y; ks[d4 + 2][m] = u.z; ks[d4 + 3][m] = u.w;
            }
            __syncthreads();
#pragma unroll 4
            for (int d = 0; d < 32; ++d) {
                float4 a0 = *(const float4*)&qs[d][ty * 4];
                float4 a1 = *(const float4*)&qs[d][64 + ty * 4];
                float4 b0 = *(const float4*)&ks[d][tx * 4];
                float4 b1 = *(const float4*)&ks[d][64 + tx * 4];
                float av[8] = {a0.x, a0.y, a0.z, a0.w, a1.x, a1.y, a1.z, a1.w};
                float bv2[8] = {b0.x, b0.y, b0.z, b0.w, b1.x, b1.y, b1.z, b1.w};
#pragma unroll
                for (int i = 0; i < 8; ++i)
#pragma unroll
                    for (int j = 0; j < 8; ++j) acc[i][j] = fmaf(av[i], bv2[j], acc[i][j]);
            }
        }
#pragma unroll
        for (int i = 0; i < 8; ++i) {
            float s = 0.f;
#pragma unroll
            for (int j = 0; j < 8; ++j) s += __expf(acc[i][j] * SCALE);
            rsum[i] += s;
        }
    }
    // reduce rsum across tx; reuse ks as [128][16] scratch (8KB <= 16.5KB)
    __syncthreads();
    float* red = &ks[0][0];
#pragma unroll
    for (int i = 0; i < 8; ++i) {
        int row = ty * 4 + (i & 3) + (i >> 2) * 64;
        red[row * 16 + tx] = rsum[i];
    }
    __syncthreads();
    if (t < 128) {
        float s = 0.f;
#pragma unroll
        for (int x2 = 0; x2 < 16; ++x2) s += red[t * 16 + x2];
        atomicAdd(&l[b * NTOK + q0 + t], s);
    }
}

// ---------------- pass 2: w[b,k] += sum_q exp(scale*s)/l[q] ----------------
__global__ __launch_bounds__(256) void score_pass2(const float* __restrict__ Q,
                                                   const float* __restrict__ K,
                                                   const float* __restrict__ l,
                                                   float* __restrict__ w) {
    const int b = blockIdx.z;
    const int q0 = blockIdx.x * 128;
    const int kbase = blockIdx.y * 2048;
    const int t = threadIdx.x;
    const int tx = t & 15, ty = t >> 4;
    const float* Qb = Q + (size_t)b * NTOK * HDIM;
    const float* Kb = K + (size_t)b * NTOK * HDIM;

    __shared__ float qs[32][132];
    __shared__ float ks[32][132];
    __shared__ float linv_s[128];

    if (t < 128) linv_s[t] = 1.f / l[b * NTOK + q0 + t];

    for (int kt = 0; kt < 16; ++kt) {
        const int k0 = kbase + kt * 128;
        float acc[8][8];
#pragma unroll
        for (int i = 0; i < 8; ++i)
#pragma unroll
            for (int j = 0; j < 8; ++j) acc[i][j] = 0.f;

        for (int dc = 0; dc < 8; ++dc) {
            const int dbase = dc * 32;
            __syncthreads();
#pragma unroll
            for (int i = 0; i < 4; ++i) {
                int f = t + i * 256;
                int m = f >> 3;
                int d4 = (f & 7) << 2;
                float4 v = *(const float4*)(Qb + (size_t)(q0 + m) * HDIM + dbase + d4);
                qs[d4 + 0][m] = v.x; qs[d4 + 1][m] = v.y; qs[d4 + 2][m] = v.z; qs[d4 + 3][m] = v.w;
                float4 u = *(const float4*)(Kb + (size_t)(k0 + m) * HDIM + dbase + d4);
                ks[d4 + 0][m] = u.x; ks[d4 + 1][m] = u.y; ks[d4 + 2][m] = u.z; ks[d4 + 3][m] = u.w;
            }
            __syncthreads();
#pragma unroll 4
            for (int d = 0; d < 32; ++d) {
                float4 a0 = *(const float4*)&qs[d][ty * 4];
                float4 a1 = *(const float4*)&qs[d][64 + ty * 4];
                float4 b0 = *(const float4*)&ks[d][tx * 4];
                float4 b1 = *(const float4*)&ks[d][64 + tx * 4];
                float av[8] = {a0.x, a0.y, a0.z, a0.w, a1.x, a1.y, a1.z, a1.w};
                float bv2[8] = {b0.x, b0.y, b0.z, b0.w, b1.x, b1.y, b1.z, b1.w};
#pragma unroll
                for (int i = 0; i < 8; ++i)
#pragma unroll
                    for (int j = 0; j < 8; ++j) acc[i][j] = fmaf(av[i], bv2[j], acc[i][j]);
            }
        }
        // p = exp(s)/l_q ; column partial sums over this block's 128 q rows
        float csum[8];
#pragma unroll
        for (int j = 0; j < 8; ++j) csum[j] = 0.f;
#pragma unroll
        for (int i = 0; i < 8; ++i) {
            int row = ty * 4 + (i & 3) + (i >> 2) * 64;
            float pl = linv_s[row];
#pragma unroll
            for (int j = 0; j < 8; ++j) csum[j] += __expf(acc[i][j] * SCALE) * pl;
        }
        __syncthreads();
        float* red = &ks[0][0];
#pragma unroll
        for (int j = 0; j < 8; ++j) {
            int col = tx * 4 + (j & 3) + (j >> 2) * 64;
            red[col * 16 + ty] = csum[j];
        }
        __syncthreads();
        if (t < 128) {
            float s = 0.f;
#pragma unroll
            for (int y = 0; y < 16; ++y) s += red[t * 16 + y];
            atomicAdd(&w[b * NTOK + k0 + t], s);
        }
        // next iteration's pre-stage __syncthreads protects red/ks overwrite
    }
}

// ---------------- finalize: out[b,h] = (1/N) sum_k w[b,k] V[b,k,h] ----------------
__global__ __launch_bounds__(256) void finalize_kernel(const float* __restrict__ V,
                                                       const float* __restrict__ w,
                                                       float* __restrict__ out) {
    const int b = blockIdx.y;
    const int k0 = blockIdx.x * 256;
    const int h = threadIdx.x;
    __shared__ float wsh[256];
    wsh[h] = w[b * NTOK + k0 + h];
    __syncthreads();
    const float* Vb = V + ((size_t)b * NTOK + k0) * HDIM;
    float acc = 0.f;
#pragma unroll 4
    for (int kk = 0; kk < 256; ++kk) acc = fmaf(wsh[kk], Vb[(size_t)kk * HDIM + h], acc);
    atomicAdd(&out[b * HDIM + h], acc * (1.0f / (float)NTOK));
}

extern "C" void kernel_launch(void* const* d_in, const int* in_sizes, int n_in,
                              void* d_out, int out_size, void* d_ws, size_t ws_size,
                              hipStream_t stream) {
    const float* x  = (const float*)d_in[0];
    const float* Wq = (const float*)d_in[1];
    const float* bq = (const float*)d_in[2];
    const float* Wk = (const float*)d_in[3];
    const float* bk = (const float*)d_in[4];
    const float* Wv = (const float*)d_in[5];
    const float* bv = (const float*)d_in[6];
    float* out = (float*)d_out;

    // workspace layout (fp32): Q, K, V [8*4096*256] each, l [8*4096], w [8*4096]  (~96.3 MiB)
    float* ws = (float*)d_ws;
    const size_t BNH = (size_t)NBATCH * NTOK * HDIM;
    float* Q = ws;
    float* K = Q + BNH;
    float* V = K + BNH;
    float* l = V + BNH;
    float* w = l + (size_t)NBATCH * NTOK;

    zero_kernel<<<dim3(128), dim3(256), 0, stream>>>(w, l, out);
    qkv_gemm<<<dim3(256, 2, 3), dim3(256), 0, stream>>>(x, Wq, bq, Wk, bk, Wv, bv, Q, K, V);
    score_pass1<<<dim3(32, 2, 8), dim3(256), 0, stream>>>(Q, K, l);
    score_pass2<<<dim3(32, 2, 8), dim3(256), 0, stream>>>(Q, K, l, w);
    finalize_kernel<<<dim3(16, 8), dim3(256), 0, stream>>>(V, w, out);
}

// Round 3
// 400.498 us; speedup vs baseline: 4.9474x; 4.9474x over previous
//
#include <hip/hip_runtime.h>
#include <hip/hip_bf16.h>

// B=8, N=4096, D=H=256. out[b,h] = sum_k w[b,k]*V[b,k,h],
//   w[b,k] = (1/N) sum_q exp(scale*s_qk)/l_q,  l_q = sum_k exp(scale*s_qk)
// Scores are small (|scale*s| < ~3) -> exp without max-subtraction is safe in fp32.
// Scores computed with bf16 MFMA (32x32x16): err ~2e-3 in s -> ~3e-5 in out (thr 1.7e-3).

#define NTOK 4096
#define HDIM 256
#define NBATCH 8
#define SCALE 0.0625f  // 1/sqrt(256)

typedef __attribute__((ext_vector_type(8))) short short8_t;   // 8 bf16 (4 VGPRs)
typedef __attribute__((ext_vector_type(16))) float f32x16;    // 32x32 C/D frag

__device__ __forceinline__ unsigned short f2bf(float f) {
    unsigned u = __float_as_uint(f);
    u += 0x7fff + ((u >> 16) & 1);   // RNE
    return (unsigned short)(u >> 16);
}

// ---------------- zero init ----------------
__global__ void zero_kernel(float* __restrict__ w, float* __restrict__ l, float* __restrict__ out) {
    int i = blockIdx.x * 256 + threadIdx.x;  // 128 blocks -> 32768
    w[i] = 0.f;
    l[i] = 0.f;
    if (i < NBATCH * HDIM) out[i] = 0.f;
}

// ---------------- fp32 -> bf16 for x ----------------
__global__ void convert_x(const float* __restrict__ x, unsigned short* __restrict__ xbf) {
    int i = (blockIdx.x * 256 + threadIdx.x) * 4;
    float4 v = *(const float4*)(x + i);
    ushort4 o;
    o.x = f2bf(v.x); o.y = f2bf(v.y); o.z = f2bf(v.z); o.w = f2bf(v.w);
    *(ushort4*)(xbf + i) = o;
}

// ---------------- W[k][n] -> Wt[n][k] bf16 (B-fragment wants contiguous k) ----------------
__global__ void convert_wt(const float* __restrict__ Wq, const float* __restrict__ Wk,
                           const float* __restrict__ Wv, unsigned short* __restrict__ Wt) {
    int z = blockIdx.y;
    const float* W = (z == 0) ? Wq : (z == 1) ? Wk : Wv;
    unsigned short* o = Wt + z * 65536;
    int n = threadIdx.x;
    for (int kk = 0; kk < 32; ++kk) {
        int k = blockIdx.x * 32 + kk;
        o[n * 256 + k] = f2bf(W[k * 256 + n]);  // coalesced read over n
    }
}

// stage 128 rows x 64 bf16 cols from row-major (stride 256) global into LDS [128][72]
__device__ __forceinline__ void stage_tile(unsigned short* __restrict__ dst,
                                           const unsigned short* __restrict__ src,
                                           int row0, int dbase, int t) {
#pragma unroll
    for (int i = 0; i < 4; ++i) {
        int f = t + i * 256;
        int r = f >> 3;
        int c8 = (f & 7) * 8;
        *(uint4*)(dst + r * 72 + c8) = *(const uint4*)(src + (size_t)(row0 + r) * HDIM + dbase + c8);
    }
}

#define MFMA(a, b, c) __builtin_amdgcn_mfma_f32_32x32x16_bf16(a, b, c, 0, 0, 0)

// ---------------- QKV projection via MFMA ----------------
__global__ __launch_bounds__(256) void qkv_mfma(const unsigned short* __restrict__ xbf,
                                                const unsigned short* __restrict__ Wt,
                                                const float* __restrict__ bq, const float* __restrict__ bk,
                                                const float* __restrict__ bv,
                                                unsigned short* __restrict__ Qbf,
                                                unsigned short* __restrict__ Kbf,
                                                float* __restrict__ Vf) {
    const int z = blockIdx.z;
    const unsigned short* Wz = Wt + z * 65536;
    const float* bias = (z == 0) ? bq : (z == 1) ? bk : bv;
    const int m0 = blockIdx.x * 128, n0 = blockIdx.y * 128;
    const int t = threadIdx.x, wv_ = t >> 6, l = t & 63, lo = l & 31, hi = l >> 5;
    const int wq = (wv_ & 1) * 64, wk = (wv_ >> 1) * 64;

    __shared__ __align__(16) char smem[36864];
    unsigned short* Xs = (unsigned short*)smem;   // [128][72]
    unsigned short* Ws = Xs + 128 * 72;           // [128][72]

    f32x16 acc[2][2];
#pragma unroll
    for (int a = 0; a < 2; ++a)
#pragma unroll
        for (int b = 0; b < 2; ++b)
#pragma unroll
            for (int r = 0; r < 16; ++r) acc[a][b][r] = 0.f;

    for (int dc = 0; dc < 4; ++dc) {
        __syncthreads();
        stage_tile(Xs, xbf, m0, dc * 64, t);
        stage_tile(Ws, Wz, n0, dc * 64, t);
        __syncthreads();
#pragma unroll
        for (int ks = 0; ks < 4; ++ks) {
            int kidx = ks * 16 + hi * 8;
            short8_t a0 = *(const short8_t*)(Xs + (wq + lo) * 72 + kidx);
            short8_t a1 = *(const short8_t*)(Xs + (wq + 32 + lo) * 72 + kidx);
            short8_t b0 = *(const short8_t*)(Ws + (wk + lo) * 72 + kidx);
            short8_t b1 = *(const short8_t*)(Ws + (wk + 32 + lo) * 72 + kidx);
            acc[0][0] = MFMA(a0, b0, acc[0][0]);
            acc[0][1] = MFMA(a0, b1, acc[0][1]);
            acc[1][0] = MFMA(a1, b0, acc[1][0]);
            acc[1][1] = MFMA(a1, b1, acc[1][1]);
        }
    }
    float bc0 = bias[n0 + wk + lo];
    float bc1 = bias[n0 + wk + 32 + lo];
#pragma unroll
    for (int mb = 0; mb < 2; ++mb)
#pragma unroll
        for (int r = 0; r < 16; ++r) {
            int row = m0 + wq + mb * 32 + (r & 3) + 8 * (r >> 2) + 4 * hi;
            int c0 = n0 + wk + lo, c1 = n0 + wk + 32 + lo;
            float v0 = acc[mb][0][r] + bc0;
            float v1 = acc[mb][1][r] + bc1;
            if (z == 2) {
                Vf[(size_t)row * HDIM + c0] = v0;
                Vf[(size_t)row * HDIM + c1] = v1;
            } else {
                unsigned short* o = (z == 0) ? Qbf : Kbf;
                o[(size_t)row * HDIM + c0] = f2bf(v0);
                o[(size_t)row * HDIM + c1] = f2bf(v1);
            }
        }
}

// ---------------- pass 1: l[b,q] = sum_k exp(scale*s) ; block = 128 q rows, loops k ----------------
__global__ __launch_bounds__(256) void score_pass1(const unsigned short* __restrict__ Qbf,
                                                   const unsigned short* __restrict__ Kbf,
                                                   float* __restrict__ lsum) {
    const int b = blockIdx.z;
    const int q0 = blockIdx.x * 128;
    const int khalf = blockIdx.y;
    const int t = threadIdx.x, wv_ = t >> 6, l = t & 63, lo = l & 31, hi = l >> 5;
    const int wq = (wv_ & 1) * 64, wk = (wv_ >> 1) * 64;
    const unsigned short* Qb = Qbf + (size_t)b * NTOK * HDIM;
    const unsigned short* Kb = Kbf + (size_t)b * NTOK * HDIM;

    __shared__ __align__(16) char smem[36864];
    unsigned short* Qs = (unsigned short*)smem;  // [128][72]
    unsigned short* Ks = Qs + 128 * 72;          // [128][72]

    f32x16 rs[2];
#pragma unroll
    for (int mb = 0; mb < 2; ++mb)
#pragma unroll
        for (int r = 0; r < 16; ++r) rs[mb][r] = 0.f;

    for (int kt = 0; kt < 16; ++kt) {
        const int k0 = khalf * 2048 + kt * 128;
        f32x16 acc[2][2];
#pragma unroll
        for (int a = 0; a < 2; ++a)
#pragma unroll
            for (int c = 0; c < 2; ++c)
#pragma unroll
                for (int r = 0; r < 16; ++r) acc[a][c][r] = 0.f;

        for (int dc = 0; dc < 4; ++dc) {
            __syncthreads();
            stage_tile(Qs, Qb, q0, dc * 64, t);
            stage_tile(Ks, Kb, k0, dc * 64, t);
            __syncthreads();
#pragma unroll
            for (int ks = 0; ks < 4; ++ks) {
                int kidx = ks * 16 + hi * 8;
                short8_t a0 = *(const short8_t*)(Qs + (wq + lo) * 72 + kidx);
                short8_t a1 = *(const short8_t*)(Qs + (wq + 32 + lo) * 72 + kidx);
                short8_t b0 = *(const short8_t*)(Ks + (wk + lo) * 72 + kidx);
                short8_t b1 = *(const short8_t*)(Ks + (wk + 32 + lo) * 72 + kidx);
                acc[0][0] = MFMA(a0, b0, acc[0][0]);
                acc[0][1] = MFMA(a0, b1, acc[0][1]);
                acc[1][0] = MFMA(a1, b0, acc[1][0]);
                acc[1][1] = MFMA(a1, b1, acc[1][1]);
            }
        }
#pragma unroll
        for (int mb = 0; mb < 2; ++mb)
#pragma unroll
            for (int r = 0; r < 16; ++r)
                rs[mb][r] += __expf(acc[mb][0][r] * SCALE) + __expf(acc[mb][1][r] * SCALE);
    }
    // reduce: row sums across 32 lanes and the two k-half waves
    __syncthreads();
    float* red = (float*)smem;  // [128][65]
#pragma unroll
    for (int mb = 0; mb < 2; ++mb)
#pragma unroll
        for (int r = 0; r < 16; ++r) {
            int row = wq + mb * 32 + (r & 3) + 8 * (r >> 2) + 4 * hi;
            red[row * 65 + (wv_ >> 1) * 32 + lo] = rs[mb][r];
        }
    __syncthreads();
    if (t < 128) {
        float s = 0.f;
#pragma unroll 8
        for (int j = 0; j < 64; ++j) s += red[t * 65 + j];
        atomicAdd(&lsum[b * NTOK + q0 + t], s);
    }
}

// ---------------- pass 2: w[b,k] += sum_q exp(scale*s)/l_q ; block = 128 k cols, loops q ----------------
__global__ __launch_bounds__(256) void score_pass2(const unsigned short* __restrict__ Qbf,
                                                   const unsigned short* __restrict__ Kbf,
                                                   const float* __restrict__ lsum,
                                                   float* __restrict__ wsum) {
    const int b = blockIdx.z;
    const int k0 = blockIdx.x * 128;
    const int qhalf = blockIdx.y;
    const int t = threadIdx.x, wv_ = t >> 6, l = t & 63, lo = l & 31, hi = l >> 5;
    const int wq = (wv_ & 1) * 64, wk = (wv_ >> 1) * 64;
    const unsigned short* Qb = Qbf + (size_t)b * NTOK * HDIM;
    const unsigned short* Kb = Kbf + (size_t)b * NTOK * HDIM;

    __shared__ __align__(16) char smem[36864];
    __shared__ float linv_s[128];
    unsigned short* Qs = (unsigned short*)smem;
    unsigned short* Ks = Qs + 128 * 72;

    float cs0 = 0.f, cs1 = 0.f;

    for (int qt = 0; qt < 16; ++qt) {
        const int q0 = qhalf * 2048 + qt * 128;
        f32x16 acc[2][2];
#pragma unroll
        for (int a = 0; a < 2; ++a)
#pragma unroll
            for (int c = 0; c < 2; ++c)
#pragma unroll
                for (int r = 0; r < 16; ++r) acc[a][c][r] = 0.f;

        for (int dc = 0; dc < 4; ++dc) {
            __syncthreads();
            stage_tile(Qs, Qb, q0, dc * 64, t);
            stage_tile(Ks, Kb, k0, dc * 64, t);
            if (dc == 0 && t < 128) linv_s[t] = 1.0f / lsum[b * NTOK + q0 + t];
            __syncthreads();
#pragma unroll
            for (int ks = 0; ks < 4; ++ks) {
                int kidx = ks * 16 + hi * 8;
                short8_t a0 = *(const short8_t*)(Qs + (wq + lo) * 72 + kidx);
                short8_t a1 = *(const short8_t*)(Qs + (wq + 32 + lo) * 72 + kidx);
                short8_t b0 = *(const short8_t*)(Ks + (wk + lo) * 72 + kidx);
                short8_t b1 = *(const short8_t*)(Ks + (wk + 32 + lo) * 72 + kidx);
                acc[0][0] = MFMA(a0, b0, acc[0][0]);
                acc[0][1] = MFMA(a0, b1, acc[0][1]);
                acc[1][0] = MFMA(a1, b0, acc[1][0]);
                acc[1][1] = MFMA(a1, b1, acc[1][1]);
            }
        }
#pragma unroll
        for (int mb = 0; mb < 2; ++mb)
#pragma unroll
            for (int r = 0; r < 16; ++r) {
                float li = linv_s[wq + mb * 32 + (r & 3) + 8 * (r >> 2) + 4 * hi];
                cs0 += __expf(acc[mb][0][r] * SCALE) * li;
                cs1 += __expf(acc[mb][1][r] * SCALE) * li;
            }
    }
    // reduce column sums: (wv_&1, hi) are the 4 row-partials for each col
    __syncthreads();
    float* red2 = (float*)smem;  // [128][5]
    red2[(wk + lo) * 5 + (wv_ & 1) * 2 + hi] = cs0;
    red2[(wk + 32 + lo) * 5 + (wv_ & 1) * 2 + hi] = cs1;
    __syncthreads();
    if (t < 128) {
        float s = red2[t * 5 + 0] + red2[t * 5 + 1] + red2[t * 5 + 2] + red2[t * 5 + 3];
        atomicAdd(&wsum[b * NTOK + k0 + t], s);
    }
}

// ---------------- finalize: out[b,h] = (1/N) sum_k w[b,k] V[b,k,h] ----------------
__global__ __launch_bounds__(256) void finalize_kernel(const float* __restrict__ V,
                                                       const float* __restrict__ w,
                                                       float* __restrict__ out) {
    const int b = blockIdx.y;
    const int k0 = blockIdx.x * 256;
    const int h = threadIdx.x;
    __shared__ float wsh[256];
    wsh[h] = w[b * NTOK + k0 + h];
    __syncthreads();
    const float* Vb = V + ((size_t)b * NTOK + k0) * HDIM;
    float acc = 0.f;
#pragma unroll 4
    for (int kk = 0; kk < 256; ++kk) acc = fmaf(wsh[kk], Vb[(size_t)kk * HDIM + h], acc);
    atomicAdd(&out[b * HDIM + h], acc * (1.0f / (float)NTOK));
}

extern "C" void kernel_launch(void* const* d_in, const int* in_sizes, int n_in,
                              void* d_out, int out_size, void* d_ws, size_t ws_size,
                              hipStream_t stream) {
    const float* x  = (const float*)d_in[0];
    const float* Wq = (const float*)d_in[1];
    const float* bq = (const float*)d_in[2];
    const float* Wk = (const float*)d_in[3];
    const float* bk = (const float*)d_in[4];
    const float* Wv = (const float*)d_in[5];
    const float* bv = (const float*)d_in[6];
    float* out = (float*)d_out;

    const size_t BNH = (size_t)NBATCH * NTOK * HDIM;  // 8388608
    unsigned short* xbf = (unsigned short*)d_ws;       // bf16 x
    unsigned short* Wt  = xbf + BNH;                   // 3 transposed bf16 weights
    unsigned short* Qbf = Wt + 3 * 65536;
    unsigned short* Kbf = Qbf + BNH;
    float* Vf   = (float*)(Kbf + BNH);                 // fp32 V
    float* lsum = Vf + BNH;                            // [8*4096]
    float* wsum = lsum + (size_t)NBATCH * NTOK;        // [8*4096]

    zero_kernel<<<dim3(128), dim3(256), 0, stream>>>(wsum, lsum, out);
    convert_x<<<dim3(8192), dim3(256), 0, stream>>>(x, xbf);
    convert_wt<<<dim3(8, 3), dim3(256), 0, stream>>>(Wq, Wk, Wv, Wt);
    qkv_mfma<<<dim3(256, 2, 3), dim3(256), 0, stream>>>(xbf, Wt, bq, bk, bv, Qbf, Kbf, Vf);
    score_pass1<<<dim3(32, 2, 8), dim3(256), 0, stream>>>(Qbf, Kbf, lsum);
    score_pass2<<<dim3(32, 2, 8), dim3(256), 0, stream>>>(Qbf, Kbf, lsum, wsum);
    finalize_kernel<<<dim3(16, 8), dim3(256), 0, stream>>>(Vf, wsum, out);
}

// Round 4
// 353.164 us; speedup vs baseline: 5.6105x; 1.1340x over previous
//
#include <hip/hip_runtime.h>
#include <hip/hip_bf16.h>

// B=8, N=4096, D=H=256. out[b,h] = sum_k w[b,k]*V[b,k,h],
//   w[b,k] = (1/N) sum_q exp(scale*s_qk)/l_q,  l_q = sum_k exp(scale*s_qk)
// Scores are small (|scale*s| < ~3) -> exp without max-subtraction is safe in fp32.
// Scores computed with bf16 MFMA (32x32x16): err ~2e-3 in s -> ~5e-4 in out (thr 1.7e-3).
// R3: 8-way split of the streamed dim in both score passes (grid 512->2048 blocks)
//     to lift residency from 2 to 4 blocks/CU (LDS-bound at 36.5KB/block).

#define NTOK 4096
#define HDIM 256
#define NBATCH 8
#define SCALE 0.0625f  // 1/sqrt(256)

typedef __attribute__((ext_vector_type(8))) short short8_t;   // 8 bf16 (4 VGPRs)
typedef __attribute__((ext_vector_type(16))) float f32x16;    // 32x32 C/D frag

__device__ __forceinline__ unsigned short f2bf(float f) {
    unsigned u = __float_as_uint(f);
    u += 0x7fff + ((u >> 16) & 1);   // RNE
    return (unsigned short)(u >> 16);
}

// ---------------- zero init ----------------
__global__ void zero_kernel(float* __restrict__ w, float* __restrict__ l, float* __restrict__ out) {
    int i = blockIdx.x * 256 + threadIdx.x;  // 128 blocks -> 32768
    w[i] = 0.f;
    l[i] = 0.f;
    if (i < NBATCH * HDIM) out[i] = 0.f;
}

// ---------------- fp32 -> bf16 for x ----------------
__global__ void convert_x(const float* __restrict__ x, unsigned short* __restrict__ xbf) {
    int i = (blockIdx.x * 256 + threadIdx.x) * 4;
    float4 v = *(const float4*)(x + i);
    ushort4 o;
    o.x = f2bf(v.x); o.y = f2bf(v.y); o.z = f2bf(v.z); o.w = f2bf(v.w);
    *(ushort4*)(xbf + i) = o;
}

// ---------------- W[k][n] -> Wt[n][k] bf16 (B-fragment wants contiguous k) ----------------
__global__ void convert_wt(const float* __restrict__ Wq, const float* __restrict__ Wk,
                           const float* __restrict__ Wv, unsigned short* __restrict__ Wt) {
    int z = blockIdx.y;
    const float* W = (z == 0) ? Wq : (z == 1) ? Wk : Wv;
    unsigned short* o = Wt + z * 65536;
    int n = threadIdx.x;
    for (int kk = 0; kk < 32; ++kk) {
        int k = blockIdx.x * 32 + kk;
        o[n * 256 + k] = f2bf(W[k * 256 + n]);  // coalesced read over n
    }
}

// stage 128 rows x 64 bf16 cols from row-major (stride 256) global into LDS [128][72]
__device__ __forceinline__ void stage_tile(unsigned short* __restrict__ dst,
                                           const unsigned short* __restrict__ src,
                                           int row0, int dbase, int t) {
#pragma unroll
    for (int i = 0; i < 4; ++i) {
        int f = t + i * 256;
        int r = f >> 3;
        int c8 = (f & 7) * 8;
        *(uint4*)(dst + r * 72 + c8) = *(const uint4*)(src + (size_t)(row0 + r) * HDIM + dbase + c8);
    }
}

#define MFMA(a, b, c) __builtin_amdgcn_mfma_f32_32x32x16_bf16(a, b, c, 0, 0, 0)

// ---------------- QKV projection via MFMA ----------------
__global__ __launch_bounds__(256) void qkv_mfma(const unsigned short* __restrict__ xbf,
                                                const unsigned short* __restrict__ Wt,
                                                const float* __restrict__ bq, const float* __restrict__ bk,
                                                const float* __restrict__ bv,
                                                unsigned short* __restrict__ Qbf,
                                                unsigned short* __restrict__ Kbf,
                                                float* __restrict__ Vf) {
    const int z = blockIdx.z;
    const unsigned short* Wz = Wt + z * 65536;
    const float* bias = (z == 0) ? bq : (z == 1) ? bk : bv;
    const int m0 = blockIdx.x * 128, n0 = blockIdx.y * 128;
    const int t = threadIdx.x, wv_ = t >> 6, l = t & 63, lo = l & 31, hi = l >> 5;
    const int wq = (wv_ & 1) * 64, wk = (wv_ >> 1) * 64;

    __shared__ __align__(16) char smem[36864];
    unsigned short* Xs = (unsigned short*)smem;   // [128][72]
    unsigned short* Ws = Xs + 128 * 72;           // [128][72]

    f32x16 acc[2][2];
#pragma unroll
    for (int a = 0; a < 2; ++a)
#pragma unroll
        for (int b = 0; b < 2; ++b)
#pragma unroll
            for (int r = 0; r < 16; ++r) acc[a][b][r] = 0.f;

    for (int dc = 0; dc < 4; ++dc) {
        __syncthreads();
        stage_tile(Xs, xbf, m0, dc * 64, t);
        stage_tile(Ws, Wz, n0, dc * 64, t);
        __syncthreads();
#pragma unroll
        for (int ks = 0; ks < 4; ++ks) {
            int kidx = ks * 16 + hi * 8;
            short8_t a0 = *(const short8_t*)(Xs + (wq + lo) * 72 + kidx);
            short8_t a1 = *(const short8_t*)(Xs + (wq + 32 + lo) * 72 + kidx);
            short8_t b0 = *(const short8_t*)(Ws + (wk + lo) * 72 + kidx);
            short8_t b1 = *(const short8_t*)(Ws + (wk + 32 + lo) * 72 + kidx);
            acc[0][0] = MFMA(a0, b0, acc[0][0]);
            acc[0][1] = MFMA(a0, b1, acc[0][1]);
            acc[1][0] = MFMA(a1, b0, acc[1][0]);
            acc[1][1] = MFMA(a1, b1, acc[1][1]);
        }
    }
    float bc0 = bias[n0 + wk + lo];
    float bc1 = bias[n0 + wk + 32 + lo];
#pragma unroll
    for (int mb = 0; mb < 2; ++mb)
#pragma unroll
        for (int r = 0; r < 16; ++r) {
            int row = m0 + wq + mb * 32 + (r & 3) + 8 * (r >> 2) + 4 * hi;
            int c0 = n0 + wk + lo, c1 = n0 + wk + 32 + lo;
            float v0 = acc[mb][0][r] + bc0;
            float v1 = acc[mb][1][r] + bc1;
            if (z == 2) {
                Vf[(size_t)row * HDIM + c0] = v0;
                Vf[(size_t)row * HDIM + c1] = v1;
            } else {
                unsigned short* o = (z == 0) ? Qbf : Kbf;
                o[(size_t)row * HDIM + c0] = f2bf(v0);
                o[(size_t)row * HDIM + c1] = f2bf(v1);
            }
        }
}

// ---------------- pass 1: l[b,q] = sum_k exp(scale*s) ; block = 128 q rows, 512 k ----------------
__global__ __launch_bounds__(256) void score_pass1(const unsigned short* __restrict__ Qbf,
                                                   const unsigned short* __restrict__ Kbf,
                                                   float* __restrict__ lsum) {
    const int b = blockIdx.z;
    const int q0 = blockIdx.x * 128;
    const int kslice = blockIdx.y;   // 0..7, 512 k each
    const int t = threadIdx.x, wv_ = t >> 6, l = t & 63, lo = l & 31, hi = l >> 5;
    const int wq = (wv_ & 1) * 64, wk = (wv_ >> 1) * 64;
    const unsigned short* Qb = Qbf + (size_t)b * NTOK * HDIM;
    const unsigned short* Kb = Kbf + (size_t)b * NTOK * HDIM;

    __shared__ __align__(16) char smem[36864];
    unsigned short* Qs = (unsigned short*)smem;  // [128][72]
    unsigned short* Ks = Qs + 128 * 72;          // [128][72]

    f32x16 rs[2];
#pragma unroll
    for (int mb = 0; mb < 2; ++mb)
#pragma unroll
        for (int r = 0; r < 16; ++r) rs[mb][r] = 0.f;

    for (int kt = 0; kt < 4; ++kt) {
        const int k0 = kslice * 512 + kt * 128;
        f32x16 acc[2][2];
#pragma unroll
        for (int a = 0; a < 2; ++a)
#pragma unroll
            for (int c = 0; c < 2; ++c)
#pragma unroll
                for (int r = 0; r < 16; ++r) acc[a][c][r] = 0.f;

        for (int dc = 0; dc < 4; ++dc) {
            __syncthreads();
            stage_tile(Qs, Qb, q0, dc * 64, t);
            stage_tile(Ks, Kb, k0, dc * 64, t);
            __syncthreads();
#pragma unroll
            for (int ks = 0; ks < 4; ++ks) {
                int kidx = ks * 16 + hi * 8;
                short8_t a0 = *(const short8_t*)(Qs + (wq + lo) * 72 + kidx);
                short8_t a1 = *(const short8_t*)(Qs + (wq + 32 + lo) * 72 + kidx);
                short8_t b0 = *(const short8_t*)(Ks + (wk + lo) * 72 + kidx);
                short8_t b1 = *(const short8_t*)(Ks + (wk + 32 + lo) * 72 + kidx);
                acc[0][0] = MFMA(a0, b0, acc[0][0]);
                acc[0][1] = MFMA(a0, b1, acc[0][1]);
                acc[1][0] = MFMA(a1, b0, acc[1][0]);
                acc[1][1] = MFMA(a1, b1, acc[1][1]);
            }
        }
#pragma unroll
        for (int mb = 0; mb < 2; ++mb)
#pragma unroll
            for (int r = 0; r < 16; ++r)
                rs[mb][r] += __expf(acc[mb][0][r] * SCALE) + __expf(acc[mb][1][r] * SCALE);
    }
    // reduce: row sums across 32 lanes and the two k-half waves
    __syncthreads();
    float* red = (float*)smem;  // [128][65]
#pragma unroll
    for (int mb = 0; mb < 2; ++mb)
#pragma unroll
        for (int r = 0; r < 16; ++r) {
            int row = wq + mb * 32 + (r & 3) + 8 * (r >> 2) + 4 * hi;
            red[row * 65 + (wv_ >> 1) * 32 + lo] = rs[mb][r];
        }
    __syncthreads();
    if (t < 128) {
        float s = 0.f;
#pragma unroll 8
        for (int j = 0; j < 64; ++j) s += red[t * 65 + j];
        atomicAdd(&lsum[b * NTOK + q0 + t], s);
    }
}

// ---------------- pass 2: w[b,k] += sum_q exp(scale*s)/l_q ; block = 128 k cols, 512 q ----------------
__global__ __launch_bounds__(256) void score_pass2(const unsigned short* __restrict__ Qbf,
                                                   const unsigned short* __restrict__ Kbf,
                                                   const float* __restrict__ lsum,
                                                   float* __restrict__ wsum) {
    const int b = blockIdx.z;
    const int k0 = blockIdx.x * 128;
    const int qslice = blockIdx.y;   // 0..7, 512 q each
    const int t = threadIdx.x, wv_ = t >> 6, l = t & 63, lo = l & 31, hi = l >> 5;
    const int wq = (wv_ & 1) * 64, wk = (wv_ >> 1) * 64;
    const unsigned short* Qb = Qbf + (size_t)b * NTOK * HDIM;
    const unsigned short* Kb = Kbf + (size_t)b * NTOK * HDIM;

    __shared__ __align__(16) char smem[36864];
    __shared__ float linv_s[128];
    unsigned short* Qs = (unsigned short*)smem;
    unsigned short* Ks = Qs + 128 * 72;

    float cs0 = 0.f, cs1 = 0.f;

    for (int qt = 0; qt < 4; ++qt) {
        const int q0 = qslice * 512 + qt * 128;
        f32x16 acc[2][2];
#pragma unroll
        for (int a = 0; a < 2; ++a)
#pragma unroll
            for (int c = 0; c < 2; ++c)
#pragma unroll
                for (int r = 0; r < 16; ++r) acc[a][c][r] = 0.f;

        for (int dc = 0; dc < 4; ++dc) {
            __syncthreads();
            stage_tile(Qs, Qb, q0, dc * 64, t);
            stage_tile(Ks, Kb, k0, dc * 64, t);
            if (dc == 0 && t < 128) linv_s[t] = 1.0f / lsum[b * NTOK + q0 + t];
            __syncthreads();
#pragma unroll
            for (int ks = 0; ks < 4; ++ks) {
                int kidx = ks * 16 + hi * 8;
                short8_t a0 = *(const short8_t*)(Qs + (wq + lo) * 72 + kidx);
                short8_t a1 = *(const short8_t*)(Qs + (wq + 32 + lo) * 72 + kidx);
                short8_t b0 = *(const short8_t*)(Ks + (wk + lo) * 72 + kidx);
                short8_t b1 = *(const short8_t*)(Ks + (wk + 32 + lo) * 72 + kidx);
                acc[0][0] = MFMA(a0, b0, acc[0][0]);
                acc[0][1] = MFMA(a0, b1, acc[0][1]);
                acc[1][0] = MFMA(a1, b0, acc[1][0]);
                acc[1][1] = MFMA(a1, b1, acc[1][1]);
            }
        }
#pragma unroll
        for (int mb = 0; mb < 2; ++mb)
#pragma unroll
            for (int r = 0; r < 16; ++r) {
                float li = linv_s[wq + mb * 32 + (r & 3) + 8 * (r >> 2) + 4 * hi];
                cs0 += __expf(acc[mb][0][r] * SCALE) * li;
                cs1 += __expf(acc[mb][1][r] * SCALE) * li;
            }
    }
    // reduce column sums: (wv_&1, hi) are the 4 row-partials for each col
    __syncthreads();
    float* red2 = (float*)smem;  // [128][5]
    red2[(wk + lo) * 5 + (wv_ & 1) * 2 + hi] = cs0;
    red2[(wk + 32 + lo) * 5 + (wv_ & 1) * 2 + hi] = cs1;
    __syncthreads();
    if (t < 128) {
        float s = red2[t * 5 + 0] + red2[t * 5 + 1] + red2[t * 5 + 2] + red2[t * 5 + 3];
        atomicAdd(&wsum[b * NTOK + k0 + t], s);
    }
}

// ---------------- finalize: out[b,h] = (1/N) sum_k w[b,k] V[b,k,h] ----------------
__global__ __launch_bounds__(256) void finalize_kernel(const float* __restrict__ V,
                                                       const float* __restrict__ w,
                                                       float* __restrict__ out) {
    const int b = blockIdx.y;
    const int k0 = blockIdx.x * 256;
    const int h = threadIdx.x;
    __shared__ float wsh[256];
    wsh[h] = w[b * NTOK + k0 + h];
    __syncthreads();
    const float* Vb = V + ((size_t)b * NTOK + k0) * HDIM;
    float acc = 0.f;
#pragma unroll 4
    for (int kk = 0; kk < 256; ++kk) acc = fmaf(wsh[kk], Vb[(size_t)kk * HDIM + h], acc);
    atomicAdd(&out[b * HDIM + h], acc * (1.0f / (float)NTOK));
}

extern "C" void kernel_launch(void* const* d_in, const int* in_sizes, int n_in,
                              void* d_out, int out_size, void* d_ws, size_t ws_size,
                              hipStream_t stream) {
    const float* x  = (const float*)d_in[0];
    const float* Wq = (const float*)d_in[1];
    const float* bq = (const float*)d_in[2];
    const float* Wk = (const float*)d_in[3];
    const float* bk = (const float*)d_in[4];
    const float* Wv = (const float*)d_in[5];
    const float* bv = (const float*)d_in[6];
    float* out = (float*)d_out;

    const size_t BNH = (size_t)NBATCH * NTOK * HDIM;  // 8388608
    unsigned short* xbf = (unsigned short*)d_ws;       // bf16 x
    unsigned short* Wt  = xbf + BNH;                   // 3 transposed bf16 weights
    unsigned short* Qbf = Wt + 3 * 65536;
    unsigned short* Kbf = Qbf + BNH;
    float* Vf   = (float*)(Kbf + BNH);                 // fp32 V
    float* lsum = Vf + BNH;                            // [8*4096]
    float* wsum = lsum + (size_t)NBATCH * NTOK;        // [8*4096]

    zero_kernel<<<dim3(128), dim3(256), 0, stream>>>(wsum, lsum, out);
    convert_x<<<dim3(8192), dim3(256), 0, stream>>>(x, xbf);
    convert_wt<<<dim3(8, 3), dim3(256), 0, stream>>>(Wq, Wk, Wv, Wt);
    qkv_mfma<<<dim3(256, 2, 3), dim3(256), 0, stream>>>(xbf, Wt, bq, bk, bv, Qbf, Kbf, Vf);
    score_pass1<<<dim3(32, 8, 8), dim3(256), 0, stream>>>(Qbf, Kbf, lsum);
    score_pass2<<<dim3(32, 8, 8), dim3(256), 0, stream>>>(Qbf, Kbf, lsum, wsum);
    finalize_kernel<<<dim3(16, 8), dim3(256), 0, stream>>>(Vf, wsum, out);
}